// Round 17
// baseline (162.996 us; speedup 1.0000x reference)
//
#include <hip/hip_runtime.h>
#include <cfloat>

// Problem constants (B=8, S=2048, D=256, K=8192)
#define N_TOK 16384
#define DIM 256
#define KCB 8192
#define BETA_C 0.25f
#define NSPLIT 4           // col splits: 2048 cols per block (R17: halved block count)
#define NCHUNK 64          // 16 k-tiles x 4 d-chunks of 64
#define MARGIN 4.0f        // exact-rescore margin (~40 sigma of bf16 dist error)

typedef __attribute__((ext_vector_type(8))) short short8;   // 8 bf16 (4 VGPRs)
typedef __attribute__((ext_vector_type(4))) float f32x4;    // MFMA acc
typedef unsigned short ushort_t;

__device__ __forceinline__ void async_copy16(const void* g, void* l) {
    __builtin_amdgcn_global_load_lds(
        (const __attribute__((address_space(1))) unsigned int*)g,
        (__attribute__((address_space(3))) unsigned int*)l, 16, 0, 0);
}

// top-2 merge with lowest-index tie-break (R4-proven logic)
__device__ __forceinline__ void merge2(float& v1, int& i1, float& v2, int& i2,
                                       float b1, int j1, float b2, int j2) {
    const bool bf_ = (b1 < v1) || (b1 == v1 && j1 < i1);
    const float nv1 = bf_ ? b1 : v1; const int ni1 = bf_ ? j1 : i1;
    const float c = bf_ ? v1 : b1;   const int ci = bf_ ? i1 : j1;
    const float d = bf_ ? b2 : v2;   const int di = bf_ ? j2 : i2;
    const bool ds_ = (d < c) || (d == c && di < ci);
    v1 = nv1; i1 = ni1;
    v2 = ds_ ? d : c; i2 = ds_ ? di : ci;
}

// ---------------- fused prep: emb->E2+enorm | x->X2 | W1->W1T | W2->W2T --------
// One launch replaces 4 (R15-proven). Block-range dispatch; uniform within block.
__global__ void __launch_bounds__(256)
prep_all_kernel(const float* __restrict__ x, const float* __restrict__ emb,
                const float* __restrict__ W1, const float* __restrict__ W2,
                ushort_t* __restrict__ X2, ushort_t* __restrict__ E2,
                float* __restrict__ enorm, ushort_t* __restrict__ W1T,
                ushort_t* __restrict__ W2T) {
    const int b = blockIdx.x;
    const int tid = threadIdx.x;
    if (b < 6144) {   // bf16-truncate rows: [0,2048) emb (+norm), [2048,6144) x
        const int w = tid >> 6, lane = tid & 63;
        const bool is_e = (b < 2048);
        const int r = (is_e ? b : (b - 2048)) * 4 + w;
        const float* src = is_e ? emb : x;
        ushort_t* dst = is_e ? E2 : X2;
        const float4 v = *reinterpret_cast<const float4*>(src + (size_t)r * DIM + lane * 4);
        const unsigned u0 = __float_as_uint(v.x), u1 = __float_as_uint(v.y);
        const unsigned u2 = __float_as_uint(v.z), u3 = __float_as_uint(v.w);
        *reinterpret_cast<uint2*>(dst + (size_t)r * DIM + lane * 4) =
            make_uint2((u0 >> 16) | (u1 & 0xFFFF0000u), (u2 >> 16) | (u3 & 0xFFFF0000u));
        if (is_e) {
            float s = v.x * v.x + v.y * v.y + v.z * v.z + v.w * v.w;
#pragma unroll
            for (int o = 32; o > 0; o >>= 1) s += __shfl_down(s, o, 64);
            if (lane == 0) enorm[r] = s;
        }
    } else {          // [6144,6400) W1 transpose, [6400,6656) W2 transpose
        const bool w1 = (b < 6400);
        const int flat = (w1 ? (b - 6144) : (b - 6400)) * 256 + tid;
        const int d = flat >> 8, e = flat & 255;
        const float* W = w1 ? W1 : W2;
        ushort_t* WT = w1 ? W1T : W2T;
        WT[(size_t)e * 256 + d] = (ushort_t)(__float_as_uint(W[flat]) >> 16);
    }
}

// ---------------- MFMA distance GEMM (R13/R16-proven inner loop) ----------------
// Block: 256 thr (4 waves 2x2), 128 rows x 2048 cols (16 k-tiles of 128), K=256 in
// 4 d-chunks of 64 -> 64 double-buffered chunk-steps; 2 blocks/CU, ONE round
// (512 blocks) -- halves per-CU prologue/epilogue cost vs NSPLIT=8.
// Counted vmcnt(8) (never 0 mid-loop); single lgkmcnt(0) phase.
// dist = ||e||^2 - 2*x.e (row-const ||x||^2 dropped; enorm exact f32, in LDS).
__global__ void __launch_bounds__(256, 2)
dist_kernel(const ushort_t* __restrict__ X2, const ushort_t* __restrict__ E2,
            const float* __restrict__ enorm, uint4* __restrict__ mg) {
    __shared__ char sb[65536];      // A bufs @0,16K; B bufs @32K,48K; epilogue sc = all
    __shared__ float enormS[2048];  // block's col-span norms (8 KB)

    const int tid = threadIdx.x;
    const int lane = tid & 63;
    const int w = tid >> 6;
    const int wy = w >> 1, wx = w & 1;
    const int l15 = lane & 15, l4 = lane >> 4;
    const int row0 = blockIdx.x * 128;
    const int col_base = blockIdx.y * 2048;      // global code col
    const int rr = lane >> 3;
    const int egr = (lane & 7) ^ rr;             // pre-swizzled source granule

    // preload enorm span once (oldest vmem ops; retired by the prologue vmcnt)
#pragma unroll
    for (int i = 0; i < 8; ++i) enormS[tid + 256 * i] = enorm[col_base + tid + 256 * i];

    float tv1[16], tv2[16];
    int ti1[16], ti2[16];
#pragma unroll
    for (int s = 0; s < 16; ++s) { tv1[s] = FLT_MAX; tv2[s] = FLT_MAX; ti1[s] = 0; ti2[s] = 0; }

    f32x4 acc[4][4];

    // chunk c -> (k-tile kt = c>>2, d-quarter dq = c&3)
#define STAGE_CHUNK(buf, c)                                                        \
    {                                                                              \
        const int kt_ = (c) >> 2, dq_ = (c) & 3;                                   \
        const int off_ = dq_ * 64;                                                 \
        const ushort_t* Ab_ = X2 + (size_t)row0 * DIM + off_ + egr * 8;            \
        const ushort_t* Bb_ = E2 + (size_t)(col_base + kt_ * 128) * DIM + off_ + egr * 8; \
        char* Al_ = sb + (buf) * 16384;                                            \
        char* Bl_ = sb + 32768 + (buf) * 16384;                                    \
        _Pragma("unroll")                                                          \
        for (int i_ = 0; i_ < 4; ++i_) {                                           \
            const int g_ = w * 4 + i_;                                             \
            async_copy16(Ab_ + (size_t)(g_ * 8 + rr) * DIM, Al_ + g_ * 1024);      \
            async_copy16(Bb_ + (size_t)(g_ * 8 + rr) * DIM, Bl_ + g_ * 1024);      \
        }                                                                          \
    }

    // prologue: chunks 0,1 in flight; retire chunk 0's 8 loads (in-order)
    STAGE_CHUNK(0, 0)
    STAGE_CHUNK(1, 1)
    asm volatile("s_waitcnt vmcnt(8)" ::: "memory");
    __builtin_amdgcn_s_barrier();

    for (int c = 0; c < NCHUNK; ++c) {
        const int cur = c & 1;
        const int cp = c & 3;

        if (cp == 0) {
#pragma unroll
            for (int m = 0; m < 4; ++m)
#pragma unroll
                for (int n = 0; n < 4; ++n) {
                    f32x4 z = {0.f, 0.f, 0.f, 0.f};
                    acc[m][n] = z;
                }
        }

        const char* Al = sb + cur * 16384;
        const char* Bl = sb + 32768 + cur * 16384;

        // read ALL frags for this chunk (16 x ds_read_b128)
        short8 af[2][4], bf[2][4];
#pragma unroll
        for (int ks = 0; ks < 2; ++ks) {
#pragma unroll
            for (int m = 0; m < 4; ++m) {
                const int r = wy * 64 + m * 16 + l15;
                af[ks][m] = *reinterpret_cast<const short8*>(
                    Al + r * 128 + ((ks * 64 + l4 * 16) ^ ((r & 7) << 4)));
            }
#pragma unroll
            for (int n = 0; n < 4; ++n) {
                const int r = wx * 64 + n * 16 + l15;
                bf[ks][n] = *reinterpret_cast<const short8*>(
                    Bl + r * 128 + ((ks * 64 + l4 * 16) ^ ((r & 7) << 4)));
            }
        }
        asm volatile("s_waitcnt lgkmcnt(0)" ::: "memory");   // this thread's reads done
        __builtin_amdgcn_sched_barrier(0);
        __builtin_amdgcn_s_barrier();                        // ALL waves done with buf cur
        if (c + 2 < NCHUNK) STAGE_CHUNK(cur, c + 2)          // restage same buf
        __builtin_amdgcn_sched_barrier(0);

        __builtin_amdgcn_s_setprio(1);
#pragma unroll
        for (int ks = 0; ks < 2; ++ks)
#pragma unroll
            for (int m = 0; m < 4; ++m)
#pragma unroll
                for (int n = 0; n < 4; ++n)
                    acc[m][n] = __builtin_amdgcn_mfma_f32_16x16x32_bf16(
                        af[ks][m], bf[ks][n], acc[m][n], 0, 0, 0);
        __builtin_amdgcn_s_setprio(0);

        if (cp == 3) {   // k-tile complete: dist = enormS - 2*dot; branchless top-2
            const int klocal = (c >> 2) * 128;
#pragma unroll
            for (int n = 0; n < 4; ++n) {
                const int cl = klocal + wx * 64 + n * 16 + l15;
                const float en = enormS[cl];
                const int kg = col_base + cl;
#pragma unroll
                for (int m = 0; m < 4; ++m)
#pragma unroll
                    for (int j = 0; j < 4; ++j) {
                        const float v = fmaf(-2.f, acc[m][n][j], en);
                        const int s = m * 4 + j;
                        const bool c1 = v < tv1[s];
                        const bool c2 = v < tv2[s];
                        tv2[s] = c1 ? tv1[s] : (c2 ? v : tv2[s]);
                        ti2[s] = c1 ? ti1[s] : (c2 ? kg : ti2[s]);
                        tv1[s] = c1 ? v : tv1[s];
                        ti1[s] = c1 ? kg : ti1[s];
                    }
            }
        }

        // counted wait: retire chunk c+1's loads, keep chunk c+2's in flight
        if (c == NCHUNK - 2) { asm volatile("s_waitcnt vmcnt(0)" ::: "memory"); }
        else if (c < NCHUNK - 2) { asm volatile("s_waitcnt vmcnt(8)" ::: "memory"); }
        __builtin_amdgcn_s_barrier();
    }

    // block-level merge: 32 contributors per row -> top-2 (conflict-free layout)
    uint4* sc = reinterpret_cast<uint4*>(sb);   // sc[thr + 256*s]
#pragma unroll
    for (int s = 0; s < 16; ++s)
        sc[tid + 256 * s] = make_uint4(__float_as_uint(tv1[s]), (unsigned)ti1[s],
                                       __float_as_uint(tv2[s]), (unsigned)ti2[s]);
    __syncthreads();
    if (tid < 128) {
        const int r = tid;
        const int wy2 = r >> 6, lr = r & 63;
        const int m = lr >> 4, g = (lr & 15) >> 2, j = lr & 3, s = m * 4 + j;
        float v1 = FLT_MAX, v2 = FLT_MAX;
        int i1 = 0, i2 = 0;
        for (int wx2 = 0; wx2 < 2; ++wx2)
            for (int c = 0; c < 16; ++c) {
                const int thr = (wy2 * 2 + wx2) * 64 + g * 16 + c;
                const uint4 q = sc[thr + 256 * s];
                const float a1 = __uint_as_float(q.x), a2 = __uint_as_float(q.z);
                if (a1 < v1) {
                    if (a2 < v1) { v1 = a1; i1 = (int)q.y; v2 = a2; i2 = (int)q.w; }
                    else { v2 = v1; i2 = i1; v1 = a1; i1 = (int)q.y; }
                } else if (a1 < v2) { v2 = a1; i2 = (int)q.y; }
            }
        mg[(size_t)(row0 + r) * NSPLIT + blockIdx.y] =
            make_uint4(__float_as_uint(v1), (unsigned)i1, __float_as_uint(v2), (unsigned)i2);
    }
}

// ---- fused rescore + MLP: idx = margin-rescore(mg); z = e + MLP(x - e) --------
// Block: 64 rows, 4 waves. Prologue: each wave rescores its 16 rows (R14-proven
// logic, 8 candidates = 4 splits x top-2), writes idxs to LDS + minq to global.
// Then the R4-proven MLP body (h lives only in LDS, bf16).
__global__ void __launch_bounds__(256)
fused_mlp_kernel(const float* __restrict__ x, const float* __restrict__ emb,
                 const uint4* __restrict__ mg, const ushort_t* __restrict__ W1T,
                 const ushort_t* __restrict__ W2T, const float* __restrict__ b1,
                 const float* __restrict__ b2, float* __restrict__ minq,
                 float* __restrict__ z) {
    __shared__ char sb[65536];
    __shared__ int idxs[64];

    const int tid = threadIdx.x;
    const int lane = tid & 63;
    const int w = tid >> 6;
    const int l15 = lane & 15, l4 = lane >> 4;
    const int rr = lane >> 3;
    const int egr = (lane & 7) ^ rr;
    const int row0 = blockIdx.x * 64;

    // ---- rescore: wave w handles rows w*16 .. w*16+15 ----
    for (int rloc = 0; rloc < 16; ++rloc) {
        const int row_l = w * 16 + rloc;
        const int n = row0 + row_l;
        const uint4 q = mg[(size_t)n * NSPLIT + (lane & 3)];
        const float v = (lane < 32) ? __uint_as_float(q.x) : __uint_as_float(q.z);
        const int ki = (lane < 32) ? (int)q.y : (int)q.w;

        float mn = v;
#pragma unroll
        for (int o = 1; o < 64; o <<= 1) mn = fminf(mn, __shfl_xor(mn, o, 64));

        const unsigned long long mask = __ballot(v <= mn + MARGIN && (lane & 31) < NSPLIT);
        const float4 xv = *reinterpret_cast<const float4*>(x + (size_t)n * DIM + lane * 4);

        float bestv = FLT_MAX;
        int bestk = 0x7fffffff;
        unsigned long long mm = mask;
        while (mm) {
            const int src = __ffsll((long long)mm) - 1;
            mm &= mm - 1;
            const int k = __shfl(ki, src, 64);
            const float4 ev = *reinterpret_cast<const float4*>(emb + (size_t)k * DIM + lane * 4);
            const float dx = xv.x - ev.x, dy = xv.y - ev.y, dz = xv.z - ev.z, dw = xv.w - ev.w;
            float s = dx * dx + dy * dy + dz * dz + dw * dw;
#pragma unroll
            for (int o = 32; o > 0; o >>= 1) s += __shfl_xor(s, o, 64);
            if (s < bestv || (s == bestv && k < bestk)) { bestv = s; bestk = k; }
        }
        if (lane == 0) {
            idxs[row_l] = bestk;
            minq[n] = bestv;
        }
    }
    __syncthreads();

    // ---- stage r = bf16(x - emb[idx]) into swizzled [64][256]-bf16 tile ----
#pragma unroll
    for (int j = 0; j < 16; ++j) {
        const int flat = tid + 256 * j;
        const int r = flat >> 6;
        const int sg = flat & 63;
        const float4 xv = *reinterpret_cast<const float4*>(x + (size_t)(row0 + r) * DIM + sg * 4);
        const float4 ev = *reinterpret_cast<const float4*>(emb + (size_t)idxs[r] * DIM + sg * 4);
        const unsigned u0 = __float_as_uint(xv.x - ev.x), u1 = __float_as_uint(xv.y - ev.y);
        const unsigned u2 = __float_as_uint(xv.z - ev.z), u3 = __float_as_uint(xv.w - ev.w);
        const uint2 pk = make_uint2((u0 >> 16) | (u1 & 0xFFFF0000u),
                                    (u2 >> 16) | (u3 & 0xFFFF0000u));
        *reinterpret_cast<uint2*>(sb + r * 512 + ((sg * 8) ^ ((r & 7) << 4))) = pk;
    }

    const ushort_t* Wp[2] = {W1T, W2T};
    f32x4 acc[4][4];

    for (int layer = 0; layer < 2; ++layer) {
        const ushort_t* WT = Wp[layer];
#pragma unroll
        for (int m = 0; m < 4; ++m)
#pragma unroll
            for (int n = 0; n < 4; ++n) {
                f32x4 zz = {0.f, 0.f, 0.f, 0.f};
                acc[m][n] = zz;
            }
        for (int kc = 0; kc < 4; ++kc) {
            __syncthreads();
#pragma unroll
            for (int i = 0; i < 8; ++i) {
                const int g = w * 8 + i;
                async_copy16(WT + (size_t)(g * 8 + rr) * 256 + kc * 64 + egr * 8,
                             sb + 32768 + g * 1024);
            }
            __syncthreads();
#pragma unroll
            for (int ks = 0; ks < 2; ++ks) {
                short8 af[4], bf[4];
#pragma unroll
                for (int m = 0; m < 4; ++m) {
                    const int r = m * 16 + l15;
                    af[m] = *reinterpret_cast<const short8*>(
                        sb + r * 512 + ((((kc * 2 + ks) * 64) + l4 * 16) ^ ((r & 7) << 4)));
                }
#pragma unroll
                for (int n = 0; n < 4; ++n) {
                    const int r = w * 64 + n * 16 + l15;
                    bf[n] = *reinterpret_cast<const short8*>(
                        sb + 32768 + r * 128 + ((ks * 64 + l4 * 16) ^ ((r & 7) << 4)));
                }
#pragma unroll
                for (int m = 0; m < 4; ++m)
#pragma unroll
                    for (int n = 0; n < 4; ++n)
                        acc[m][n] = __builtin_amdgcn_mfma_f32_16x16x32_bf16(af[m], bf[n], acc[m][n], 0, 0, 0);
            }
        }

        if (layer == 0) {
            float b1v[4];
#pragma unroll
            for (int n = 0; n < 4; ++n) b1v[n] = b1[w * 64 + n * 16 + l15];
            __syncthreads();
#pragma unroll
            for (int m = 0; m < 4; ++m)
#pragma unroll
                for (int n = 0; n < 4; ++n)
#pragma unroll
                    for (int j = 0; j < 4; ++j) {
                        const int row = m * 16 + l4 * 4 + j;
                        const int col = w * 64 + n * 16 + l15;
                        const float hv = fmaxf(acc[m][n][j] + b1v[n], 0.f);
                        *reinterpret_cast<ushort_t*>(
                            sb + row * 512 + ((col * 2) ^ ((row & 7) << 4))) =
                            (ushort_t)(__float_as_uint(hv) >> 16);
                    }
            __syncthreads();
        } else {
            float b2v[4];
#pragma unroll
            for (int n = 0; n < 4; ++n) b2v[n] = b2[w * 64 + n * 16 + l15];
#pragma unroll
            for (int m = 0; m < 4; ++m)
#pragma unroll
                for (int n = 0; n < 4; ++n)
#pragma unroll
                    for (int j = 0; j < 4; ++j) {
                        const int row = m * 16 + l4 * 4 + j;
                        const int col = w * 64 + n * 16 + l15;
                        const float ev = emb[(size_t)idxs[row] * DIM + col];
                        z[(size_t)(row0 + row) * DIM + col] = acc[m][n][j] + b2v[n] + ev;
                    }
        }
    }
}

// ---------------- loss: BETA * mean(exact min dist) ----------------
__global__ void loss_kernel(const float* __restrict__ minq, float* __restrict__ loss_out) {
    const int tid = threadIdx.x;
    float s = 0.f;
    for (int i = tid; i < N_TOK; i += 256) s += minq[i];
#pragma unroll
    for (int o = 32; o > 0; o >>= 1) s += __shfl_down(s, o, 64);
    __shared__ float sbf[4];
    if ((tid & 63) == 0) sbf[tid >> 6] = s;
    __syncthreads();
    if (tid == 0) loss_out[0] = BETA_C * ((sbf[0] + sbf[1] + sbf[2] + sbf[3]) / (float)N_TOK);
}

extern "C" void kernel_launch(void* const* d_in, const int* in_sizes, int n_in,
                              void* d_out, int out_size, void* d_ws, size_t ws_size,
                              hipStream_t stream) {
    const float* x   = (const float*)d_in[0];
    const float* emb = (const float*)d_in[1];
    const float* W1  = (const float*)d_in[2];
    const float* b1  = (const float*)d_in[3];
    const float* W2  = (const float*)d_in[4];
    const float* b2  = (const float*)d_in[5];

    float* z_out = (float*)d_out;
    float* loss_out = z_out + (size_t)N_TOK * DIM;

    // workspace (14.1 MB, all disjoint; proven budget >= 17.0 MB):
    //   [0,32K) enorm | [96K,160K) minq
    //   [160K,288K) W1T | [288K,416K) W2T
    //   [425984, +4M)  E2 [8192][256] bf16
    //   [4620288, +8M) X2 [16384][256] bf16
    //   [13008896, +1M) mg [16384][4] uint4
    char* ws = (char*)d_ws;
    float*    enorm = (float*)(ws);
    float*    minq  = (float*)(ws + 98304);
    ushort_t* W1T   = (ushort_t*)(ws + 163840);
    ushort_t* W2T   = (ushort_t*)(ws + 294912);
    ushort_t* E2    = (ushort_t*)(ws + 425984);
    ushort_t* X2    = (ushort_t*)(ws + 4620288);
    uint4*    mg    = (uint4*)(ws + 13008896);

    hipLaunchKernelGGL(prep_all_kernel, dim3(6656), dim3(256), 0, stream,
                       x, emb, W1, W2, X2, E2, enorm, W1T, W2T);
    hipLaunchKernelGGL(dist_kernel, dim3(N_TOK / 128, NSPLIT), dim3(256), 0, stream,
                       X2, E2, enorm, mg);
    hipLaunchKernelGGL(fused_mlp_kernel, dim3(N_TOK / 64), dim3(256), 0, stream,
                       x, emb, mg, W1T, W2T, b1, b2, minq, z_out);
    hipLaunchKernelGGL(loss_kernel, dim3(1), dim3(256), 0, stream, minq, loss_out);
}

// Round 18
// 149.635 us; speedup vs baseline: 1.0893x; 1.0893x over previous
//
#include <hip/hip_runtime.h>
#include <cfloat>

// Problem constants (B=8, S=2048, D=256, K=8192)
#define N_TOK 16384
#define DIM 256
#define KCB 8192
#define BETA_C 0.25f
#define NSPLIT 4           // col splits: 2048 cols per block (R17-proven)
#define NCHUNK 64          // 16 k-tiles x 4 d-chunks of 64
#define MARGIN 4.0f        // exact-rescore margin (~40 sigma of bf16 dist error)

typedef __attribute__((ext_vector_type(8))) short short8;   // 8 bf16 (4 VGPRs)
typedef __attribute__((ext_vector_type(4))) float f32x4;    // MFMA acc
typedef unsigned short ushort_t;

__device__ __forceinline__ void async_copy16(const void* g, void* l) {
    __builtin_amdgcn_global_load_lds(
        (const __attribute__((address_space(1))) unsigned int*)g,
        (__attribute__((address_space(3))) unsigned int*)l, 16, 0, 0);
}

// ---------------- fused prep: emb->E2+enorm | x->X2 | W1->W1T | W2->W2T --------
// One launch replaces 4 (R15-proven). Block-range dispatch; uniform within block.
__global__ void __launch_bounds__(256)
prep_all_kernel(const float* __restrict__ x, const float* __restrict__ emb,
                const float* __restrict__ W1, const float* __restrict__ W2,
                ushort_t* __restrict__ X2, ushort_t* __restrict__ E2,
                float* __restrict__ enorm, ushort_t* __restrict__ W1T,
                ushort_t* __restrict__ W2T) {
    const int b = blockIdx.x;
    const int tid = threadIdx.x;
    if (b < 6144) {   // bf16-truncate rows: [0,2048) emb (+norm), [2048,6144) x
        const int w = tid >> 6, lane = tid & 63;
        const bool is_e = (b < 2048);
        const int r = (is_e ? b : (b - 2048)) * 4 + w;
        const float* src = is_e ? emb : x;
        ushort_t* dst = is_e ? E2 : X2;
        const float4 v = *reinterpret_cast<const float4*>(src + (size_t)r * DIM + lane * 4);
        const unsigned u0 = __float_as_uint(v.x), u1 = __float_as_uint(v.y);
        const unsigned u2 = __float_as_uint(v.z), u3 = __float_as_uint(v.w);
        *reinterpret_cast<uint2*>(dst + (size_t)r * DIM + lane * 4) =
            make_uint2((u0 >> 16) | (u1 & 0xFFFF0000u), (u2 >> 16) | (u3 & 0xFFFF0000u));
        if (is_e) {
            float s = v.x * v.x + v.y * v.y + v.z * v.z + v.w * v.w;
#pragma unroll
            for (int o = 32; o > 0; o >>= 1) s += __shfl_down(s, o, 64);
            if (lane == 0) enorm[r] = s;
        }
    } else {          // [6144,6400) W1 transpose, [6400,6656) W2 transpose
        const bool w1 = (b < 6400);
        const int flat = (w1 ? (b - 6144) : (b - 6400)) * 256 + tid;
        const int d = flat >> 8, e = flat & 255;
        const float* W = w1 ? W1 : W2;
        ushort_t* WT = w1 ? W1T : W2T;
        WT[(size_t)e * 256 + d] = (ushort_t)(__float_as_uint(W[flat]) >> 16);
    }
}

// ---------------- MFMA distance GEMM (R17-proven: 101.5 us) ---------------------
// Block: 256 thr (4 waves 2x2), 128 rows x 2048 cols (16 k-tiles of 128), K=256 in
// 4 d-chunks of 64 -> 64 double-buffered chunk-steps; 2 blocks/CU, one round.
// Counted vmcnt(8) (never 0 mid-loop); single lgkmcnt(0) phase.
// dist = ||e||^2 - 2*x.e (row-const ||x||^2 dropped; enorm exact f32, in LDS).
__global__ void __launch_bounds__(256, 2)
dist_kernel(const ushort_t* __restrict__ X2, const ushort_t* __restrict__ E2,
            const float* __restrict__ enorm, uint4* __restrict__ mg) {
    __shared__ char sb[65536];      // A bufs @0,16K; B bufs @32K,48K; epilogue sc = all
    __shared__ float enormS[2048];  // block's col-span norms (8 KB)

    const int tid = threadIdx.x;
    const int lane = tid & 63;
    const int w = tid >> 6;
    const int wy = w >> 1, wx = w & 1;
    const int l15 = lane & 15, l4 = lane >> 4;
    const int row0 = blockIdx.x * 128;
    const int col_base = blockIdx.y * 2048;      // global code col
    const int rr = lane >> 3;
    const int egr = (lane & 7) ^ rr;             // pre-swizzled source granule

    // preload enorm span once (oldest vmem ops; retired by the prologue vmcnt)
#pragma unroll
    for (int i = 0; i < 8; ++i) enormS[tid + 256 * i] = enorm[col_base + tid + 256 * i];

    float tv1[16], tv2[16];
    int ti1[16], ti2[16];
#pragma unroll
    for (int s = 0; s < 16; ++s) { tv1[s] = FLT_MAX; tv2[s] = FLT_MAX; ti1[s] = 0; ti2[s] = 0; }

    f32x4 acc[4][4];

    // chunk c -> (k-tile kt = c>>2, d-quarter dq = c&3)
#define STAGE_CHUNK(buf, c)                                                        \
    {                                                                              \
        const int kt_ = (c) >> 2, dq_ = (c) & 3;                                   \
        const int off_ = dq_ * 64;                                                 \
        const ushort_t* Ab_ = X2 + (size_t)row0 * DIM + off_ + egr * 8;            \
        const ushort_t* Bb_ = E2 + (size_t)(col_base + kt_ * 128) * DIM + off_ + egr * 8; \
        char* Al_ = sb + (buf) * 16384;                                            \
        char* Bl_ = sb + 32768 + (buf) * 16384;                                    \
        _Pragma("unroll")                                                          \
        for (int i_ = 0; i_ < 4; ++i_) {                                           \
            const int g_ = w * 4 + i_;                                             \
            async_copy16(Ab_ + (size_t)(g_ * 8 + rr) * DIM, Al_ + g_ * 1024);      \
            async_copy16(Bb_ + (size_t)(g_ * 8 + rr) * DIM, Bl_ + g_ * 1024);      \
        }                                                                          \
    }

    // prologue: chunks 0,1 in flight; retire chunk 0's 8 loads (in-order)
    STAGE_CHUNK(0, 0)
    STAGE_CHUNK(1, 1)
    asm volatile("s_waitcnt vmcnt(8)" ::: "memory");
    __builtin_amdgcn_s_barrier();

    for (int c = 0; c < NCHUNK; ++c) {
        const int cur = c & 1;
        const int cp = c & 3;

        if (cp == 0) {
#pragma unroll
            for (int m = 0; m < 4; ++m)
#pragma unroll
                for (int n = 0; n < 4; ++n) {
                    f32x4 z = {0.f, 0.f, 0.f, 0.f};
                    acc[m][n] = z;
                }
        }

        const char* Al = sb + cur * 16384;
        const char* Bl = sb + 32768 + cur * 16384;

        // read ALL frags for this chunk (16 x ds_read_b128)
        short8 af[2][4], bf[2][4];
#pragma unroll
        for (int ks = 0; ks < 2; ++ks) {
#pragma unroll
            for (int m = 0; m < 4; ++m) {
                const int r = wy * 64 + m * 16 + l15;
                af[ks][m] = *reinterpret_cast<const short8*>(
                    Al + r * 128 + ((ks * 64 + l4 * 16) ^ ((r & 7) << 4)));
            }
#pragma unroll
            for (int n = 0; n < 4; ++n) {
                const int r = wx * 64 + n * 16 + l15;
                bf[ks][n] = *reinterpret_cast<const short8*>(
                    Bl + r * 128 + ((ks * 64 + l4 * 16) ^ ((r & 7) << 4)));
            }
        }
        asm volatile("s_waitcnt lgkmcnt(0)" ::: "memory");   // this thread's reads done
        __builtin_amdgcn_sched_barrier(0);
        __builtin_amdgcn_s_barrier();                        // ALL waves done with buf cur
        if (c + 2 < NCHUNK) STAGE_CHUNK(cur, c + 2)          // restage same buf
        __builtin_amdgcn_sched_barrier(0);

        __builtin_amdgcn_s_setprio(1);
#pragma unroll
        for (int ks = 0; ks < 2; ++ks)
#pragma unroll
            for (int m = 0; m < 4; ++m)
#pragma unroll
                for (int n = 0; n < 4; ++n)
                    acc[m][n] = __builtin_amdgcn_mfma_f32_16x16x32_bf16(
                        af[ks][m], bf[ks][n], acc[m][n], 0, 0, 0);
        __builtin_amdgcn_s_setprio(0);

        if (cp == 3) {   // k-tile complete: dist = enormS - 2*dot; branchless top-2
            const int klocal = (c >> 2) * 128;
#pragma unroll
            for (int n = 0; n < 4; ++n) {
                const int cl = klocal + wx * 64 + n * 16 + l15;
                const float en = enormS[cl];
                const int kg = col_base + cl;
#pragma unroll
                for (int m = 0; m < 4; ++m)
#pragma unroll
                    for (int j = 0; j < 4; ++j) {
                        const float v = fmaf(-2.f, acc[m][n][j], en);
                        const int s = m * 4 + j;
                        const bool c1 = v < tv1[s];
                        const bool c2 = v < tv2[s];
                        tv2[s] = c1 ? tv1[s] : (c2 ? v : tv2[s]);
                        ti2[s] = c1 ? ti1[s] : (c2 ? kg : ti2[s]);
                        tv1[s] = c1 ? v : tv1[s];
                        ti1[s] = c1 ? kg : ti1[s];
                    }
            }
        }

        // counted wait: retire chunk c+1's loads, keep chunk c+2's in flight
        if (c == NCHUNK - 2) { asm volatile("s_waitcnt vmcnt(0)" ::: "memory"); }
        else if (c < NCHUNK - 2) { asm volatile("s_waitcnt vmcnt(8)" ::: "memory"); }
        __builtin_amdgcn_s_barrier();
    }

    // block-level merge: 32 contributors per row -> top-2 (conflict-free layout)
    uint4* sc = reinterpret_cast<uint4*>(sb);   // sc[thr + 256*s]
#pragma unroll
    for (int s = 0; s < 16; ++s)
        sc[tid + 256 * s] = make_uint4(__float_as_uint(tv1[s]), (unsigned)ti1[s],
                                       __float_as_uint(tv2[s]), (unsigned)ti2[s]);
    __syncthreads();
    if (tid < 128) {
        const int r = tid;
        const int wy2 = r >> 6, lr = r & 63;
        const int m = lr >> 4, g = (lr & 15) >> 2, j = lr & 3, s = m * 4 + j;
        float v1 = FLT_MAX, v2 = FLT_MAX;
        int i1 = 0, i2 = 0;
        for (int wx2 = 0; wx2 < 2; ++wx2)
            for (int c = 0; c < 16; ++c) {
                const int thr = (wy2 * 2 + wx2) * 64 + g * 16 + c;
                const uint4 q = sc[thr + 256 * s];
                const float a1 = __uint_as_float(q.x), a2 = __uint_as_float(q.z);
                if (a1 < v1) {
                    if (a2 < v1) { v1 = a1; i1 = (int)q.y; v2 = a2; i2 = (int)q.w; }
                    else { v2 = v1; i2 = i1; v1 = a1; i1 = (int)q.y; }
                } else if (a1 < v2) { v2 = a1; i2 = (int)q.y; }
            }
        mg[(size_t)(row0 + r) * NSPLIT + blockIdx.y] =
            make_uint4(__float_as_uint(v1), (unsigned)i1, __float_as_uint(v2), (unsigned)i2);
    }
}

// ---------------- merge splits + margin-based exact f32 rescore ----------------
// One wave per row (fully parallel — R17's 16x-serialized fusion regressed):
// 8 candidates (4 splits x top-2); exact-rescore all within MARGIN of the approx
// min; argmin with lowest-index tie-break. (R14-proven form, NSPLIT=4.)
__global__ void __launch_bounds__(256)
merge_fixup_kernel(const float* __restrict__ x, const float* __restrict__ emb,
                   const uint4* __restrict__ mg, int* __restrict__ idx_out,
                   float* __restrict__ minq) {
    const int w = threadIdx.x >> 6, lane = threadIdx.x & 63;
    const int n = blockIdx.x * 4 + w;
    const uint4 q = mg[(size_t)n * NSPLIT + (lane & 3)];
    const float v = (lane < 32) ? __uint_as_float(q.x) : __uint_as_float(q.z);
    const int ki = (lane < 32) ? (int)q.y : (int)q.w;

    float m = v;
#pragma unroll
    for (int o = 1; o < 64; o <<= 1) m = fminf(m, __shfl_xor(m, o, 64));

    const unsigned long long mask = __ballot(v <= m + MARGIN && (lane & 31) < NSPLIT);
    const float4 xv = *reinterpret_cast<const float4*>(x + (size_t)n * DIM + lane * 4);

    float bestv = FLT_MAX;
    int bestk = 0x7fffffff;
    unsigned long long mm = mask;
    while (mm) {
        const int src = __ffsll((long long)mm) - 1;
        mm &= mm - 1;
        const int k = __shfl(ki, src, 64);
        const float4 ev = *reinterpret_cast<const float4*>(emb + (size_t)k * DIM + lane * 4);
        const float dx = xv.x - ev.x, dy = xv.y - ev.y, dz = xv.z - ev.z, dw = xv.w - ev.w;
        float s = dx * dx + dy * dy + dz * dz + dw * dw;
#pragma unroll
        for (int o = 32; o > 0; o >>= 1) s += __shfl_xor(s, o, 64);
        if (s < bestv || (s == bestv && k < bestk)) { bestv = s; bestk = k; }
    }
    if (lane == 0) {
        idx_out[n] = bestk;
        minq[n] = bestv;
    }
}

// ---------------- fused MLP: z = e + W2T-gemm(relu(W1T-gemm(x-e)+b1))+b2 --------
// (R4-proven) Block: 64 rows, 4 waves; h lives only in LDS (bf16).
__global__ void __launch_bounds__(256)
fused_mlp_kernel(const float* __restrict__ x, const float* __restrict__ emb,
                 const int* __restrict__ idx, const ushort_t* __restrict__ W1T,
                 const ushort_t* __restrict__ W2T, const float* __restrict__ b1,
                 const float* __restrict__ b2, float* __restrict__ z) {
    __shared__ char sb[65536];
    __shared__ int idxs[64];

    const int tid = threadIdx.x;
    const int lane = tid & 63;
    const int w = tid >> 6;
    const int l15 = lane & 15, l4 = lane >> 4;
    const int rr = lane >> 3;
    const int egr = (lane & 7) ^ rr;
    const int row0 = blockIdx.x * 64;

    if (tid < 64) idxs[tid] = idx[row0 + tid];
    __syncthreads();

#pragma unroll
    for (int j = 0; j < 16; ++j) {
        const int flat = tid + 256 * j;
        const int r = flat >> 6;
        const int sg = flat & 63;
        const float4 xv = *reinterpret_cast<const float4*>(x + (size_t)(row0 + r) * DIM + sg * 4);
        const float4 ev = *reinterpret_cast<const float4*>(emb + (size_t)idxs[r] * DIM + sg * 4);
        const unsigned u0 = __float_as_uint(xv.x - ev.x), u1 = __float_as_uint(xv.y - ev.y);
        const unsigned u2 = __float_as_uint(xv.z - ev.z), u3 = __float_as_uint(xv.w - ev.w);
        const uint2 pk = make_uint2((u0 >> 16) | (u1 & 0xFFFF0000u),
                                    (u2 >> 16) | (u3 & 0xFFFF0000u));
        *reinterpret_cast<uint2*>(sb + r * 512 + ((sg * 8) ^ ((r & 7) << 4))) = pk;
    }

    const ushort_t* Wp[2] = {W1T, W2T};
    f32x4 acc[4][4];

    for (int layer = 0; layer < 2; ++layer) {
        const ushort_t* WT = Wp[layer];
#pragma unroll
        for (int m = 0; m < 4; ++m)
#pragma unroll
            for (int n = 0; n < 4; ++n) {
                f32x4 zz = {0.f, 0.f, 0.f, 0.f};
                acc[m][n] = zz;
            }
        for (int kc = 0; kc < 4; ++kc) {
            __syncthreads();
#pragma unroll
            for (int i = 0; i < 8; ++i) {
                const int g = w * 8 + i;
                async_copy16(WT + (size_t)(g * 8 + rr) * 256 + kc * 64 + egr * 8,
                             sb + 32768 + g * 1024);
            }
            __syncthreads();
#pragma unroll
            for (int ks = 0; ks < 2; ++ks) {
                short8 af[4], bf[4];
#pragma unroll
                for (int m = 0; m < 4; ++m) {
                    const int r = m * 16 + l15;
                    af[m] = *reinterpret_cast<const short8*>(
                        sb + r * 512 + ((((kc * 2 + ks) * 64) + l4 * 16) ^ ((r & 7) << 4)));
                }
#pragma unroll
                for (int n = 0; n < 4; ++n) {
                    const int r = w * 64 + n * 16 + l15;
                    bf[n] = *reinterpret_cast<const short8*>(
                        sb + 32768 + r * 128 + ((ks * 64 + l4 * 16) ^ ((r & 7) << 4)));
                }
#pragma unroll
                for (int m = 0; m < 4; ++m)
#pragma unroll
                    for (int n = 0; n < 4; ++n)
                        acc[m][n] = __builtin_amdgcn_mfma_f32_16x16x32_bf16(af[m], bf[n], acc[m][n], 0, 0, 0);
            }
        }

        if (layer == 0) {
            float b1v[4];
#pragma unroll
            for (int n = 0; n < 4; ++n) b1v[n] = b1[w * 64 + n * 16 + l15];
            __syncthreads();
#pragma unroll
            for (int m = 0; m < 4; ++m)
#pragma unroll
                for (int n = 0; n < 4; ++n)
#pragma unroll
                    for (int j = 0; j < 4; ++j) {
                        const int row = m * 16 + l4 * 4 + j;
                        const int col = w * 64 + n * 16 + l15;
                        const float hv = fmaxf(acc[m][n][j] + b1v[n], 0.f);
                        *reinterpret_cast<ushort_t*>(
                            sb + row * 512 + ((col * 2) ^ ((row & 7) << 4))) =
                            (ushort_t)(__float_as_uint(hv) >> 16);
                    }
            __syncthreads();
        } else {
            float b2v[4];
#pragma unroll
            for (int n = 0; n < 4; ++n) b2v[n] = b2[w * 64 + n * 16 + l15];
#pragma unroll
            for (int m = 0; m < 4; ++m)
#pragma unroll
                for (int n = 0; n < 4; ++n)
#pragma unroll
                    for (int j = 0; j < 4; ++j) {
                        const int row = m * 16 + l4 * 4 + j;
                        const int col = w * 64 + n * 16 + l15;
                        const float ev = emb[(size_t)idxs[row] * DIM + col];
                        z[(size_t)(row0 + row) * DIM + col] = acc[m][n][j] + b2v[n] + ev;
                    }
        }
    }
}

// ---------------- loss: BETA * mean(exact min dist) ----------------
__global__ void loss_kernel(const float* __restrict__ minq, float* __restrict__ loss_out) {
    const int tid = threadIdx.x;
    float s = 0.f;
    for (int i = tid; i < N_TOK; i += 256) s += minq[i];
#pragma unroll
    for (int o = 32; o > 0; o >>= 1) s += __shfl_down(s, o, 64);
    __shared__ float sbf[4];
    if ((tid & 63) == 0) sbf[tid >> 6] = s;
    __syncthreads();
    if (tid == 0) loss_out[0] = BETA_C * ((sbf[0] + sbf[1] + sbf[2] + sbf[3]) / (float)N_TOK);
}

extern "C" void kernel_launch(void* const* d_in, const int* in_sizes, int n_in,
                              void* d_out, int out_size, void* d_ws, size_t ws_size,
                              hipStream_t stream) {
    const float* x   = (const float*)d_in[0];
    const float* emb = (const float*)d_in[1];
    const float* W1  = (const float*)d_in[2];
    const float* b1  = (const float*)d_in[3];
    const float* W2  = (const float*)d_in[4];
    const float* b2  = (const float*)d_in[5];

    float* z_out = (float*)d_out;
    float* loss_out = z_out + (size_t)N_TOK * DIM;

    // workspace (14.1 MB, all disjoint; proven budget >= 17.0 MB):
    //   [0,32K) enorm | [32K,96K) idx | [96K,160K) minq
    //   [160K,288K) W1T | [288K,416K) W2T
    //   [425984, +4M)  E2 [8192][256] bf16
    //   [4620288, +8M) X2 [16384][256] bf16
    //   [13008896, +1M) mg [16384][4] uint4
    char* ws = (char*)d_ws;
    float*    enorm = (float*)(ws);
    int*      idxb  = (int*)(ws + 32768);
    float*    minq  = (float*)(ws + 98304);
    ushort_t* W1T   = (ushort_t*)(ws + 163840);
    ushort_t* W2T   = (ushort_t*)(ws + 294912);
    ushort_t* E2    = (ushort_t*)(ws + 425984);
    ushort_t* X2    = (ushort_t*)(ws + 4620288);
    uint4*    mg    = (uint4*)(ws + 13008896);

    hipLaunchKernelGGL(prep_all_kernel, dim3(6656), dim3(256), 0, stream,
                       x, emb, W1, W2, X2, E2, enorm, W1T, W2T);
    hipLaunchKernelGGL(dist_kernel, dim3(N_TOK / 128, NSPLIT), dim3(256), 0, stream,
                       X2, E2, enorm, mg);
    hipLaunchKernelGGL(merge_fixup_kernel, dim3(N_TOK / 4), dim3(256), 0, stream,
                       x, emb, mg, idxb, minq);
    hipLaunchKernelGGL(fused_mlp_kernel, dim3(N_TOK / 64), dim3(256), 0, stream,
                       x, emb, idxb, W1T, W2T, b1, b2, z_out);
    hipLaunchKernelGGL(loss_kernel, dim3(1), dim3(256), 0, stream, minq, loss_out);
}

// Round 19
// 149.605 us; speedup vs baseline: 1.0895x; 1.0002x over previous
//
#include <hip/hip_runtime.h>
#include <cfloat>

// Problem constants (B=8, S=2048, D=256, K=8192)
#define N_TOK 16384
#define DIM 256
#define KCB 8192
#define BETA_C 0.25f
#define NSPLIT 4           // col splits: 2048 cols per block (R17-proven)
#define NCHUNK 64          // 16 k-tiles x 4 d-chunks of 64
#define MARGIN 4.0f        // exact-rescore margin (~40 sigma of bf16 dist error)

typedef __attribute__((ext_vector_type(8))) short short8;   // 8 bf16 (4 VGPRs)
typedef __attribute__((ext_vector_type(4))) float f32x4;    // MFMA acc
typedef unsigned short ushort_t;

__device__ __forceinline__ void async_copy16(const void* g, void* l) {
    __builtin_amdgcn_global_load_lds(
        (const __attribute__((address_space(1))) unsigned int*)g,
        (__attribute__((address_space(3))) unsigned int*)l, 16, 0, 0);
}

// ---------------- fused prep: emb->E2+enorm | x->X2 | W1->W1T | W2->W2T --------
// One launch replaces 4 (R15-proven). Block-range dispatch; uniform within block.
__global__ void __launch_bounds__(256)
prep_all_kernel(const float* __restrict__ x, const float* __restrict__ emb,
                const float* __restrict__ W1, const float* __restrict__ W2,
                ushort_t* __restrict__ X2, ushort_t* __restrict__ E2,
                float* __restrict__ enorm, ushort_t* __restrict__ W1T,
                ushort_t* __restrict__ W2T) {
    const int b = blockIdx.x;
    const int tid = threadIdx.x;
    if (b < 6144) {   // bf16-truncate rows: [0,2048) emb (+norm), [2048,6144) x
        const int w = tid >> 6, lane = tid & 63;
        const bool is_e = (b < 2048);
        const int r = (is_e ? b : (b - 2048)) * 4 + w;
        const float* src = is_e ? emb : x;
        ushort_t* dst = is_e ? E2 : X2;
        const float4 v = *reinterpret_cast<const float4*>(src + (size_t)r * DIM + lane * 4);
        const unsigned u0 = __float_as_uint(v.x), u1 = __float_as_uint(v.y);
        const unsigned u2 = __float_as_uint(v.z), u3 = __float_as_uint(v.w);
        *reinterpret_cast<uint2*>(dst + (size_t)r * DIM + lane * 4) =
            make_uint2((u0 >> 16) | (u1 & 0xFFFF0000u), (u2 >> 16) | (u3 & 0xFFFF0000u));
        if (is_e) {
            float s = v.x * v.x + v.y * v.y + v.z * v.z + v.w * v.w;
#pragma unroll
            for (int o = 32; o > 0; o >>= 1) s += __shfl_down(s, o, 64);
            if (lane == 0) enorm[r] = s;
        }
    } else {          // [6144,6400) W1 transpose, [6400,6656) W2 transpose
        const bool w1 = (b < 6400);
        const int flat = (w1 ? (b - 6144) : (b - 6400)) * 256 + tid;
        const int d = flat >> 8, e = flat & 255;
        const float* W = w1 ? W1 : W2;
        ushort_t* WT = w1 ? W1T : W2T;
        WT[(size_t)e * 256 + d] = (ushort_t)(__float_as_uint(W[flat]) >> 16);
    }
}

// ---------------- MFMA distance GEMM (R17-proven: 101.5 us) ---------------------
// Block: 256 thr (4 waves 2x2), 128 rows x 2048 cols (16 k-tiles of 128), K=256 in
// 4 d-chunks of 64 -> 64 double-buffered chunk-steps; 2 blocks/CU, one round.
// Counted vmcnt(8) (never 0 mid-loop); single lgkmcnt(0) phase.
// dist = ||e||^2 - 2*x.e (row-const ||x||^2 dropped; enorm exact f32, in LDS).
__global__ void __launch_bounds__(256, 2)
dist_kernel(const ushort_t* __restrict__ X2, const ushort_t* __restrict__ E2,
            const float* __restrict__ enorm, uint4* __restrict__ mg) {
    __shared__ char sb[65536];      // A bufs @0,16K; B bufs @32K,48K; epilogue sc = all
    __shared__ float enormS[2048];  // block's col-span norms (8 KB)

    const int tid = threadIdx.x;
    const int lane = tid & 63;
    const int w = tid >> 6;
    const int wy = w >> 1, wx = w & 1;
    const int l15 = lane & 15, l4 = lane >> 4;
    const int row0 = blockIdx.x * 128;
    const int col_base = blockIdx.y * 2048;      // global code col
    const int rr = lane >> 3;
    const int egr = (lane & 7) ^ rr;             // pre-swizzled source granule

    // preload enorm span once (oldest vmem ops; retired by the prologue vmcnt)
#pragma unroll
    for (int i = 0; i < 8; ++i) enormS[tid + 256 * i] = enorm[col_base + tid + 256 * i];

    float tv1[16], tv2[16];
    int ti1[16], ti2[16];
#pragma unroll
    for (int s = 0; s < 16; ++s) { tv1[s] = FLT_MAX; tv2[s] = FLT_MAX; ti1[s] = 0; ti2[s] = 0; }

    f32x4 acc[4][4];

    // chunk c -> (k-tile kt = c>>2, d-quarter dq = c&3)
#define STAGE_CHUNK(buf, c)                                                        \
    {                                                                              \
        const int kt_ = (c) >> 2, dq_ = (c) & 3;                                   \
        const int off_ = dq_ * 64;                                                 \
        const ushort_t* Ab_ = X2 + (size_t)row0 * DIM + off_ + egr * 8;            \
        const ushort_t* Bb_ = E2 + (size_t)(col_base + kt_ * 128) * DIM + off_ + egr * 8; \
        char* Al_ = sb + (buf) * 16384;                                            \
        char* Bl_ = sb + 32768 + (buf) * 16384;                                    \
        _Pragma("unroll")                                                          \
        for (int i_ = 0; i_ < 4; ++i_) {                                           \
            const int g_ = w * 4 + i_;                                             \
            async_copy16(Ab_ + (size_t)(g_ * 8 + rr) * DIM, Al_ + g_ * 1024);      \
            async_copy16(Bb_ + (size_t)(g_ * 8 + rr) * DIM, Bl_ + g_ * 1024);      \
        }                                                                          \
    }

    // prologue: chunks 0,1 in flight; retire chunk 0's 8 loads (in-order)
    STAGE_CHUNK(0, 0)
    STAGE_CHUNK(1, 1)
    asm volatile("s_waitcnt vmcnt(8)" ::: "memory");
    __builtin_amdgcn_s_barrier();

    for (int c = 0; c < NCHUNK; ++c) {
        const int cur = c & 1;
        const int cp = c & 3;

        if (cp == 0) {
#pragma unroll
            for (int m = 0; m < 4; ++m)
#pragma unroll
                for (int n = 0; n < 4; ++n) {
                    f32x4 z = {0.f, 0.f, 0.f, 0.f};
                    acc[m][n] = z;
                }
        }

        const char* Al = sb + cur * 16384;
        const char* Bl = sb + 32768 + cur * 16384;

        // read ALL frags for this chunk (16 x ds_read_b128)
        short8 af[2][4], bf[2][4];
#pragma unroll
        for (int ks = 0; ks < 2; ++ks) {
#pragma unroll
            for (int m = 0; m < 4; ++m) {
                const int r = wy * 64 + m * 16 + l15;
                af[ks][m] = *reinterpret_cast<const short8*>(
                    Al + r * 128 + ((ks * 64 + l4 * 16) ^ ((r & 7) << 4)));
            }
#pragma unroll
            for (int n = 0; n < 4; ++n) {
                const int r = wx * 64 + n * 16 + l15;
                bf[ks][n] = *reinterpret_cast<const short8*>(
                    Bl + r * 128 + ((ks * 64 + l4 * 16) ^ ((r & 7) << 4)));
            }
        }
        asm volatile("s_waitcnt lgkmcnt(0)" ::: "memory");   // this thread's reads done
        __builtin_amdgcn_sched_barrier(0);
        __builtin_amdgcn_s_barrier();                        // ALL waves done with buf cur
        if (c + 2 < NCHUNK) STAGE_CHUNK(cur, c + 2)          // restage same buf
        __builtin_amdgcn_sched_barrier(0);

        __builtin_amdgcn_s_setprio(1);
#pragma unroll
        for (int ks = 0; ks < 2; ++ks)
#pragma unroll
            for (int m = 0; m < 4; ++m)
#pragma unroll
                for (int n = 0; n < 4; ++n)
                    acc[m][n] = __builtin_amdgcn_mfma_f32_16x16x32_bf16(
                        af[ks][m], bf[ks][n], acc[m][n], 0, 0, 0);
        __builtin_amdgcn_s_setprio(0);

        if (cp == 3) {   // k-tile complete: dist = enormS - 2*dot; branchless top-2
            const int klocal = (c >> 2) * 128;
#pragma unroll
            for (int n = 0; n < 4; ++n) {
                const int cl = klocal + wx * 64 + n * 16 + l15;
                const float en = enormS[cl];
                const int kg = col_base + cl;
#pragma unroll
                for (int m = 0; m < 4; ++m)
#pragma unroll
                    for (int j = 0; j < 4; ++j) {
                        const float v = fmaf(-2.f, acc[m][n][j], en);
                        const int s = m * 4 + j;
                        const bool c1 = v < tv1[s];
                        const bool c2 = v < tv2[s];
                        tv2[s] = c1 ? tv1[s] : (c2 ? v : tv2[s]);
                        ti2[s] = c1 ? ti1[s] : (c2 ? kg : ti2[s]);
                        tv1[s] = c1 ? v : tv1[s];
                        ti1[s] = c1 ? kg : ti1[s];
                    }
            }
        }

        // counted wait: retire chunk c+1's loads, keep chunk c+2's in flight
        if (c == NCHUNK - 2) { asm volatile("s_waitcnt vmcnt(0)" ::: "memory"); }
        else if (c < NCHUNK - 2) { asm volatile("s_waitcnt vmcnt(8)" ::: "memory"); }
        __builtin_amdgcn_s_barrier();
    }

    // block-level merge: 32 contributors per row -> top-2 (conflict-free layout)
    uint4* sc = reinterpret_cast<uint4*>(sb);   // sc[thr + 256*s]
#pragma unroll
    for (int s = 0; s < 16; ++s)
        sc[tid + 256 * s] = make_uint4(__float_as_uint(tv1[s]), (unsigned)ti1[s],
                                       __float_as_uint(tv2[s]), (unsigned)ti2[s]);
    __syncthreads();
    if (tid < 128) {
        const int r = tid;
        const int wy2 = r >> 6, lr = r & 63;
        const int m = lr >> 4, g = (lr & 15) >> 2, j = lr & 3, s = m * 4 + j;
        float v1 = FLT_MAX, v2 = FLT_MAX;
        int i1 = 0, i2 = 0;
        for (int wx2 = 0; wx2 < 2; ++wx2)
            for (int c = 0; c < 16; ++c) {
                const int thr = (wy2 * 2 + wx2) * 64 + g * 16 + c;
                const uint4 q = sc[thr + 256 * s];
                const float a1 = __uint_as_float(q.x), a2 = __uint_as_float(q.z);
                if (a1 < v1) {
                    if (a2 < v1) { v1 = a1; i1 = (int)q.y; v2 = a2; i2 = (int)q.w; }
                    else { v2 = v1; i2 = i1; v1 = a1; i1 = (int)q.y; }
                } else if (a1 < v2) { v2 = a1; i2 = (int)q.y; }
            }
        mg[(size_t)(row0 + r) * NSPLIT + blockIdx.y] =
            make_uint4(__float_as_uint(v1), (unsigned)i1, __float_as_uint(v2), (unsigned)i2);
    }
}

// ---------------- merge splits + margin-based exact f32 rescore ----------------
// One wave per row (fully parallel — R17's 16x-serialized fusion regressed):
// 8 candidates (4 splits x top-2); exact-rescore all within MARGIN of the approx
// min; argmin with lowest-index tie-break. (R14-proven form, NSPLIT=4.)
__global__ void __launch_bounds__(256)
merge_fixup_kernel(const float* __restrict__ x, const float* __restrict__ emb,
                   const uint4* __restrict__ mg, int* __restrict__ idx_out,
                   float* __restrict__ minq) {
    const int w = threadIdx.x >> 6, lane = threadIdx.x & 63;
    const int n = blockIdx.x * 4 + w;
    const uint4 q = mg[(size_t)n * NSPLIT + (lane & 3)];
    const float v = (lane < 32) ? __uint_as_float(q.x) : __uint_as_float(q.z);
    const int ki = (lane < 32) ? (int)q.y : (int)q.w;

    float m = v;
#pragma unroll
    for (int o = 1; o < 64; o <<= 1) m = fminf(m, __shfl_xor(m, o, 64));

    const unsigned long long mask = __ballot(v <= m + MARGIN && (lane & 31) < NSPLIT);
    const float4 xv = *reinterpret_cast<const float4*>(x + (size_t)n * DIM + lane * 4);

    float bestv = FLT_MAX;
    int bestk = 0x7fffffff;
    unsigned long long mm = mask;
    while (mm) {
        const int src = __ffsll((long long)mm) - 1;
        mm &= mm - 1;
        const int k = __shfl(ki, src, 64);
        const float4 ev = *reinterpret_cast<const float4*>(emb + (size_t)k * DIM + lane * 4);
        const float dx = xv.x - ev.x, dy = xv.y - ev.y, dz = xv.z - ev.z, dw = xv.w - ev.w;
        float s = dx * dx + dy * dy + dz * dz + dw * dw;
#pragma unroll
        for (int o = 32; o > 0; o >>= 1) s += __shfl_xor(s, o, 64);
        if (s < bestv || (s == bestv && k < bestk)) { bestv = s; bestk = k; }
    }
    if (lane == 0) {
        idx_out[n] = bestk;
        minq[n] = bestv;
    }
}

// ---------------- fused MLP: z = e + W2T-gemm(relu(W1T-gemm(x-e)+b1))+b2 --------
// (R4-proven) Block: 64 rows, 4 waves; h lives only in LDS (bf16).
__global__ void __launch_bounds__(256)
fused_mlp_kernel(const float* __restrict__ x, const float* __restrict__ emb,
                 const int* __restrict__ idx, const ushort_t* __restrict__ W1T,
                 const ushort_t* __restrict__ W2T, const float* __restrict__ b1,
                 const float* __restrict__ b2, float* __restrict__ z) {
    __shared__ char sb[65536];
    __shared__ int idxs[64];

    const int tid = threadIdx.x;
    const int lane = tid & 63;
    const int w = tid >> 6;
    const int l15 = lane & 15, l4 = lane >> 4;
    const int rr = lane >> 3;
    const int egr = (lane & 7) ^ rr;
    const int row0 = blockIdx.x * 64;

    if (tid < 64) idxs[tid] = idx[row0 + tid];
    __syncthreads();

#pragma unroll
    for (int j = 0; j < 16; ++j) {
        const int flat = tid + 256 * j;
        const int r = flat >> 6;
        const int sg = flat & 63;
        const float4 xv = *reinterpret_cast<const float4*>(x + (size_t)(row0 + r) * DIM + sg * 4);
        const float4 ev = *reinterpret_cast<const float4*>(emb + (size_t)idxs[r] * DIM + sg * 4);
        const unsigned u0 = __float_as_uint(xv.x - ev.x), u1 = __float_as_uint(xv.y - ev.y);
        const unsigned u2 = __float_as_uint(xv.z - ev.z), u3 = __float_as_uint(xv.w - ev.w);
        const uint2 pk = make_uint2((u0 >> 16) | (u1 & 0xFFFF0000u),
                                    (u2 >> 16) | (u3 & 0xFFFF0000u));
        *reinterpret_cast<uint2*>(sb + r * 512 + ((sg * 8) ^ ((r & 7) << 4))) = pk;
    }

    const ushort_t* Wp[2] = {W1T, W2T};
    f32x4 acc[4][4];

    for (int layer = 0; layer < 2; ++layer) {
        const ushort_t* WT = Wp[layer];
#pragma unroll
        for (int m = 0; m < 4; ++m)
#pragma unroll
            for (int n = 0; n < 4; ++n) {
                f32x4 zz = {0.f, 0.f, 0.f, 0.f};
                acc[m][n] = zz;
            }
        for (int kc = 0; kc < 4; ++kc) {
            __syncthreads();
#pragma unroll
            for (int i = 0; i < 8; ++i) {
                const int g = w * 8 + i;
                async_copy16(WT + (size_t)(g * 8 + rr) * 256 + kc * 64 + egr * 8,
                             sb + 32768 + g * 1024);
            }
            __syncthreads();
#pragma unroll
            for (int ks = 0; ks < 2; ++ks) {
                short8 af[4], bf[4];
#pragma unroll
                for (int m = 0; m < 4; ++m) {
                    const int r = m * 16 + l15;
                    af[m] = *reinterpret_cast<const short8*>(
                        sb + r * 512 + ((((kc * 2 + ks) * 64) + l4 * 16) ^ ((r & 7) << 4)));
                }
#pragma unroll
                for (int n = 0; n < 4; ++n) {
                    const int r = w * 64 + n * 16 + l15;
                    bf[n] = *reinterpret_cast<const short8*>(
                        sb + 32768 + r * 128 + ((ks * 64 + l4 * 16) ^ ((r & 7) << 4)));
                }
#pragma unroll
                for (int m = 0; m < 4; ++m)
#pragma unroll
                    for (int n = 0; n < 4; ++n)
                        acc[m][n] = __builtin_amdgcn_mfma_f32_16x16x32_bf16(af[m], bf[n], acc[m][n], 0, 0, 0);
            }
        }

        if (layer == 0) {
            float b1v[4];
#pragma unroll
            for (int n = 0; n < 4; ++n) b1v[n] = b1[w * 64 + n * 16 + l15];
            __syncthreads();
#pragma unroll
            for (int m = 0; m < 4; ++m)
#pragma unroll
                for (int n = 0; n < 4; ++n)
#pragma unroll
                    for (int j = 0; j < 4; ++j) {
                        const int row = m * 16 + l4 * 4 + j;
                        const int col = w * 64 + n * 16 + l15;
                        const float hv = fmaxf(acc[m][n][j] + b1v[n], 0.f);
                        *reinterpret_cast<ushort_t*>(
                            sb + row * 512 + ((col * 2) ^ ((row & 7) << 4))) =
                            (ushort_t)(__float_as_uint(hv) >> 16);
                    }
            __syncthreads();
        } else {
            float b2v[4];
#pragma unroll
            for (int n = 0; n < 4; ++n) b2v[n] = b2[w * 64 + n * 16 + l15];
#pragma unroll
            for (int m = 0; m < 4; ++m)
#pragma unroll
                for (int n = 0; n < 4; ++n)
#pragma unroll
                    for (int j = 0; j < 4; ++j) {
                        const int row = m * 16 + l4 * 4 + j;
                        const int col = w * 64 + n * 16 + l15;
                        const float ev = emb[(size_t)idxs[row] * DIM + col];
                        z[(size_t)(row0 + row) * DIM + col] = acc[m][n][j] + b2v[n] + ev;
                    }
        }
    }
}

// ---------------- loss: BETA * mean(exact min dist) ----------------
__global__ void loss_kernel(const float* __restrict__ minq, float* __restrict__ loss_out) {
    const int tid = threadIdx.x;
    float s = 0.f;
    for (int i = tid; i < N_TOK; i += 256) s += minq[i];
#pragma unroll
    for (int o = 32; o > 0; o >>= 1) s += __shfl_down(s, o, 64);
    __shared__ float sbf[4];
    if ((tid & 63) == 0) sbf[tid >> 6] = s;
    __syncthreads();
    if (tid == 0) loss_out[0] = BETA_C * ((sbf[0] + sbf[1] + sbf[2] + sbf[3]) / (float)N_TOK);
}

extern "C" void kernel_launch(void* const* d_in, const int* in_sizes, int n_in,
                              void* d_out, int out_size, void* d_ws, size_t ws_size,
                              hipStream_t stream) {
    const float* x   = (const float*)d_in[0];
    const float* emb = (const float*)d_in[1];
    const float* W1  = (const float*)d_in[2];
    const float* b1  = (const float*)d_in[3];
    const float* W2  = (const float*)d_in[4];
    const float* b2  = (const float*)d_in[5];

    float* z_out = (float*)d_out;
    float* loss_out = z_out + (size_t)N_TOK * DIM;

    // workspace (14.1 MB, all disjoint; proven budget >= 17.0 MB):
    //   [0,32K) enorm | [32K,96K) idx | [96K,160K) minq
    //   [160K,288K) W1T | [288K,416K) W2T
    //   [425984, +4M)  E2 [8192][256] bf16
    //   [4620288, +8M) X2 [16384][256] bf16
    //   [13008896, +1M) mg [16384][4] uint4
    char* ws = (char*)d_ws;
    float*    enorm = (float*)(ws);
    int*      idxb  = (int*)(ws + 32768);
    float*    minq  = (float*)(ws + 98304);
    ushort_t* W1T   = (ushort_t*)(ws + 163840);
    ushort_t* W2T   = (ushort_t*)(ws + 294912);
    ushort_t* E2    = (ushort_t*)(ws + 425984);
    ushort_t* X2    = (ushort_t*)(ws + 4620288);
    uint4*    mg    = (uint4*)(ws + 13008896);

    hipLaunchKernelGGL(prep_all_kernel, dim3(6656), dim3(256), 0, stream,
                       x, emb, W1, W2, X2, E2, enorm, W1T, W2T);
    hipLaunchKernelGGL(dist_kernel, dim3(N_TOK / 128, NSPLIT), dim3(256), 0, stream,
                       X2, E2, enorm, mg);
    hipLaunchKernelGGL(merge_fixup_kernel, dim3(N_TOK / 4), dim3(256), 0, stream,
                       x, emb, mg, idxb, minq);
    hipLaunchKernelGGL(fused_mlp_kernel, dim3(N_TOK / 64), dim3(256), 0, stream,
                       x, emb, idxb, W1T, W2T, b1, b2, z_out);
    hipLaunchKernelGGL(loss_kernel, dim3(1), dim3(256), 0, stream, minq, loss_out);
}

// Round 20
// 148.822 us; speedup vs baseline: 1.0952x; 1.0053x over previous
//
#include <hip/hip_runtime.h>
#include <cfloat>

// Problem constants (B=8, S=2048, D=256, K=8192)
#define N_TOK 16384
#define DIM 256
#define KCB 8192
#define BETA_C 0.25f
#define NSPLIT 4           // col splits: 2048 cols per block (R17-proven)
#define NCHUNK 64          // 16 k-tiles x 4 d-chunks of 64
#define MARGIN 4.0f        // exact-rescore margin (~40 sigma of bf16 dist error)

typedef __attribute__((ext_vector_type(8))) short short8;   // 8 bf16 (4 VGPRs)
typedef __attribute__((ext_vector_type(4))) float f32x4;    // MFMA acc
typedef unsigned short ushort_t;

__device__ __forceinline__ void async_copy16(const void* g, void* l) {
    __builtin_amdgcn_global_load_lds(
        (const __attribute__((address_space(1))) unsigned int*)g,
        (__attribute__((address_space(3))) unsigned int*)l, 16, 0, 0);
}

// ---------------- fused prep: emb->E2+enorm | x->X2 | W1->W1T | W2->W2T --------
// One launch replaces 4 (R15-proven). Block-range dispatch; uniform within block.
__global__ void __launch_bounds__(256)
prep_all_kernel(const float* __restrict__ x, const float* __restrict__ emb,
                const float* __restrict__ W1, const float* __restrict__ W2,
                ushort_t* __restrict__ X2, ushort_t* __restrict__ E2,
                float* __restrict__ enorm, ushort_t* __restrict__ W1T,
                ushort_t* __restrict__ W2T) {
    const int b = blockIdx.x;
    const int tid = threadIdx.x;
    if (b < 6144) {   // bf16-truncate rows: [0,2048) emb (+norm), [2048,6144) x
        const int w = tid >> 6, lane = tid & 63;
        const bool is_e = (b < 2048);
        const int r = (is_e ? b : (b - 2048)) * 4 + w;
        const float* src = is_e ? emb : x;
        ushort_t* dst = is_e ? E2 : X2;
        const float4 v = *reinterpret_cast<const float4*>(src + (size_t)r * DIM + lane * 4);
        const unsigned u0 = __float_as_uint(v.x), u1 = __float_as_uint(v.y);
        const unsigned u2 = __float_as_uint(v.z), u3 = __float_as_uint(v.w);
        *reinterpret_cast<uint2*>(dst + (size_t)r * DIM + lane * 4) =
            make_uint2((u0 >> 16) | (u1 & 0xFFFF0000u), (u2 >> 16) | (u3 & 0xFFFF0000u));
        if (is_e) {
            float s = v.x * v.x + v.y * v.y + v.z * v.z + v.w * v.w;
#pragma unroll
            for (int o = 32; o > 0; o >>= 1) s += __shfl_down(s, o, 64);
            if (lane == 0) enorm[r] = s;
        }
    } else {          // [6144,6400) W1 transpose, [6400,6656) W2 transpose
        const bool w1 = (b < 6400);
        const int flat = (w1 ? (b - 6144) : (b - 6400)) * 256 + tid;
        const int d = flat >> 8, e = flat & 255;
        const float* W = w1 ? W1 : W2;
        ushort_t* WT = w1 ? W1T : W2T;
        WT[(size_t)e * 256 + d] = (ushort_t)(__float_as_uint(W[flat]) >> 16);
    }
}

// ---------------- MFMA distance GEMM (R17/R19-proven: 101.5 us) -----------------
// Block: 256 thr (4 waves 2x2), 128 rows x 2048 cols (16 k-tiles of 128), K=256 in
// 4 d-chunks of 64 -> 64 double-buffered chunk-steps; 2 blocks/CU, one round.
// Counted vmcnt(8) (never 0 mid-loop); single lgkmcnt(0) phase.
// dist = ||e||^2 - 2*x.e (row-const ||x||^2 dropped; enorm exact f32, in LDS).
__global__ void __launch_bounds__(256, 2)
dist_kernel(const ushort_t* __restrict__ X2, const ushort_t* __restrict__ E2,
            const float* __restrict__ enorm, uint4* __restrict__ mg) {
    __shared__ char sb[65536];      // A bufs @0,16K; B bufs @32K,48K; epilogue sc = all
    __shared__ float enormS[2048];  // block's col-span norms (8 KB)

    const int tid = threadIdx.x;
    const int lane = tid & 63;
    const int w = tid >> 6;
    const int wy = w >> 1, wx = w & 1;
    const int l15 = lane & 15, l4 = lane >> 4;
    const int row0 = blockIdx.x * 128;
    const int col_base = blockIdx.y * 2048;      // global code col
    const int rr = lane >> 3;
    const int egr = (lane & 7) ^ rr;             // pre-swizzled source granule

    // preload enorm span once (oldest vmem ops; retired by the prologue vmcnt)
#pragma unroll
    for (int i = 0; i < 8; ++i) enormS[tid + 256 * i] = enorm[col_base + tid + 256 * i];

    float tv1[16], tv2[16];
    int ti1[16], ti2[16];
#pragma unroll
    for (int s = 0; s < 16; ++s) { tv1[s] = FLT_MAX; tv2[s] = FLT_MAX; ti1[s] = 0; ti2[s] = 0; }

    f32x4 acc[4][4];

    // chunk c -> (k-tile kt = c>>2, d-quarter dq = c&3)
#define STAGE_CHUNK(buf, c)                                                        \
    {                                                                              \
        const int kt_ = (c) >> 2, dq_ = (c) & 3;                                   \
        const int off_ = dq_ * 64;                                                 \
        const ushort_t* Ab_ = X2 + (size_t)row0 * DIM + off_ + egr * 8;            \
        const ushort_t* Bb_ = E2 + (size_t)(col_base + kt_ * 128) * DIM + off_ + egr * 8; \
        char* Al_ = sb + (buf) * 16384;                                            \
        char* Bl_ = sb + 32768 + (buf) * 16384;                                    \
        _Pragma("unroll")                                                          \
        for (int i_ = 0; i_ < 4; ++i_) {                                           \
            const int g_ = w * 4 + i_;                                             \
            async_copy16(Ab_ + (size_t)(g_ * 8 + rr) * DIM, Al_ + g_ * 1024);      \
            async_copy16(Bb_ + (size_t)(g_ * 8 + rr) * DIM, Bl_ + g_ * 1024);      \
        }                                                                          \
    }

    // prologue: chunks 0,1 in flight; retire chunk 0's 8 loads (in-order)
    STAGE_CHUNK(0, 0)
    STAGE_CHUNK(1, 1)
    asm volatile("s_waitcnt vmcnt(8)" ::: "memory");
    __builtin_amdgcn_s_barrier();

    for (int c = 0; c < NCHUNK; ++c) {
        const int cur = c & 1;
        const int cp = c & 3;

        if (cp == 0) {
#pragma unroll
            for (int m = 0; m < 4; ++m)
#pragma unroll
                for (int n = 0; n < 4; ++n) {
                    f32x4 z = {0.f, 0.f, 0.f, 0.f};
                    acc[m][n] = z;
                }
        }

        const char* Al = sb + cur * 16384;
        const char* Bl = sb + 32768 + cur * 16384;

        // read ALL frags for this chunk (16 x ds_read_b128)
        short8 af[2][4], bf[2][4];
#pragma unroll
        for (int ks = 0; ks < 2; ++ks) {
#pragma unroll
            for (int m = 0; m < 4; ++m) {
                const int r = wy * 64 + m * 16 + l15;
                af[ks][m] = *reinterpret_cast<const short8*>(
                    Al + r * 128 + ((ks * 64 + l4 * 16) ^ ((r & 7) << 4)));
            }
#pragma unroll
            for (int n = 0; n < 4; ++n) {
                const int r = wx * 64 + n * 16 + l15;
                bf[ks][n] = *reinterpret_cast<const short8*>(
                    Bl + r * 128 + ((ks * 64 + l4 * 16) ^ ((r & 7) << 4)));
            }
        }
        asm volatile("s_waitcnt lgkmcnt(0)" ::: "memory");   // this thread's reads done
        __builtin_amdgcn_sched_barrier(0);
        __builtin_amdgcn_s_barrier();                        // ALL waves done with buf cur
        if (c + 2 < NCHUNK) STAGE_CHUNK(cur, c + 2)          // restage same buf
        __builtin_amdgcn_sched_barrier(0);

        __builtin_amdgcn_s_setprio(1);
#pragma unroll
        for (int ks = 0; ks < 2; ++ks)
#pragma unroll
            for (int m = 0; m < 4; ++m)
#pragma unroll
                for (int n = 0; n < 4; ++n)
                    acc[m][n] = __builtin_amdgcn_mfma_f32_16x16x32_bf16(
                        af[ks][m], bf[ks][n], acc[m][n], 0, 0, 0);
        __builtin_amdgcn_s_setprio(0);

        if (cp == 3) {   // k-tile complete: dist = enormS - 2*dot; branchless top-2
            const int klocal = (c >> 2) * 128;
#pragma unroll
            for (int n = 0; n < 4; ++n) {
                const int cl = klocal + wx * 64 + n * 16 + l15;
                const float en = enormS[cl];
                const int kg = col_base + cl;
#pragma unroll
                for (int m = 0; m < 4; ++m)
#pragma unroll
                    for (int j = 0; j < 4; ++j) {
                        const float v = fmaf(-2.f, acc[m][n][j], en);
                        const int s = m * 4 + j;
                        const bool c1 = v < tv1[s];
                        const bool c2 = v < tv2[s];
                        tv2[s] = c1 ? tv1[s] : (c2 ? v : tv2[s]);
                        ti2[s] = c1 ? ti1[s] : (c2 ? kg : ti2[s]);
                        tv1[s] = c1 ? v : tv1[s];
                        ti1[s] = c1 ? kg : ti1[s];
                    }
            }
        }

        // counted wait: retire chunk c+1's loads, keep chunk c+2's in flight
        if (c == NCHUNK - 2) { asm volatile("s_waitcnt vmcnt(0)" ::: "memory"); }
        else if (c < NCHUNK - 2) { asm volatile("s_waitcnt vmcnt(8)" ::: "memory"); }
        __builtin_amdgcn_s_barrier();
    }

    // block-level merge: 32 contributors per row -> top-2 (conflict-free layout)
    uint4* sc = reinterpret_cast<uint4*>(sb);   // sc[thr + 256*s]
#pragma unroll
    for (int s = 0; s < 16; ++s)
        sc[tid + 256 * s] = make_uint4(__float_as_uint(tv1[s]), (unsigned)ti1[s],
                                       __float_as_uint(tv2[s]), (unsigned)ti2[s]);
    __syncthreads();
    if (tid < 128) {
        const int r = tid;
        const int wy2 = r >> 6, lr = r & 63;
        const int m = lr >> 4, g = (lr & 15) >> 2, j = lr & 3, s = m * 4 + j;
        float v1 = FLT_MAX, v2 = FLT_MAX;
        int i1 = 0, i2 = 0;
        for (int wx2 = 0; wx2 < 2; ++wx2)
            for (int c = 0; c < 16; ++c) {
                const int thr = (wy2 * 2 + wx2) * 64 + g * 16 + c;
                const uint4 q = sc[thr + 256 * s];
                const float a1 = __uint_as_float(q.x), a2 = __uint_as_float(q.z);
                if (a1 < v1) {
                    if (a2 < v1) { v1 = a1; i1 = (int)q.y; v2 = a2; i2 = (int)q.w; }
                    else { v2 = v1; i2 = i1; v1 = a1; i1 = (int)q.y; }
                } else if (a1 < v2) { v2 = a1; i2 = (int)q.y; }
            }
        mg[(size_t)(row0 + r) * NSPLIT + blockIdx.y] =
            make_uint4(__float_as_uint(v1), (unsigned)i1, __float_as_uint(v2), (unsigned)i2);
    }
}

// ---------------- merge splits + margin-based exact f32 rescore ----------------
// One wave per row (fully parallel): 8 candidates (4 splits x top-2); exact-
// rescore all within MARGIN of the approx min; argmin, lowest-index tie-break.
__global__ void __launch_bounds__(256)
merge_fixup_kernel(const float* __restrict__ x, const float* __restrict__ emb,
                   const uint4* __restrict__ mg, int* __restrict__ idx_out,
                   float* __restrict__ minq) {
    const int w = threadIdx.x >> 6, lane = threadIdx.x & 63;
    const int n = blockIdx.x * 4 + w;
    const uint4 q = mg[(size_t)n * NSPLIT + (lane & 3)];
    const float v = (lane < 32) ? __uint_as_float(q.x) : __uint_as_float(q.z);
    const int ki = (lane < 32) ? (int)q.y : (int)q.w;

    float m = v;
#pragma unroll
    for (int o = 1; o < 64; o <<= 1) m = fminf(m, __shfl_xor(m, o, 64));

    const unsigned long long mask = __ballot(v <= m + MARGIN && (lane & 31) < NSPLIT);
    const float4 xv = *reinterpret_cast<const float4*>(x + (size_t)n * DIM + lane * 4);

    float bestv = FLT_MAX;
    int bestk = 0x7fffffff;
    unsigned long long mm = mask;
    while (mm) {
        const int src = __ffsll((long long)mm) - 1;
        mm &= mm - 1;
        const int k = __shfl(ki, src, 64);
        const float4 ev = *reinterpret_cast<const float4*>(emb + (size_t)k * DIM + lane * 4);
        const float dx = xv.x - ev.x, dy = xv.y - ev.y, dz = xv.z - ev.z, dw = xv.w - ev.w;
        float s = dx * dx + dy * dy + dz * dz + dw * dw;
#pragma unroll
        for (int o = 32; o > 0; o >>= 1) s += __shfl_xor(s, o, 64);
        if (s < bestv || (s == bestv && k < bestk)) { bestv = s; bestk = k; }
    }
    if (lane == 0) {
        idx_out[n] = bestk;
        minq[n] = bestv;
    }
}

// ---------------- fused MLP: z = e + W2T-gemm(relu(W1T-gemm(x-e)+b1))+b2 --------
// R20: 32 rows/block (grid 512), LDS 48.1 KB -> 3 blocks/CU = 12 waves/CU
// (was 64 rows, 1 block/CU = 4 waves/CU: occupancy-starved, latency-bound).
// Same proven barrier structure / swizzles / epilogues; indices halved.
__global__ void __launch_bounds__(256, 3)
fused_mlp_kernel(const float* __restrict__ x, const float* __restrict__ emb,
                 const int* __restrict__ idx, const ushort_t* __restrict__ W1T,
                 const ushort_t* __restrict__ W2T, const float* __restrict__ b1,
                 const float* __restrict__ b2, float* __restrict__ z) {
    __shared__ char sb[49152];   // [0,16K): A/h tile [32 rows][512B]; [16K,48K): W chunk
    __shared__ int idxs[32];

    const int tid = threadIdx.x;
    const int lane = tid & 63;
    const int w = tid >> 6;
    const int l15 = lane & 15, l4 = lane >> 4;
    const int rr = lane >> 3;
    const int egr = (lane & 7) ^ rr;
    const int row0 = blockIdx.x * 32;

    if (tid < 32) idxs[tid] = idx[row0 + tid];
    __syncthreads();

    // stage r = bf16(x - emb[idx]) into swizzled [32][256]-bf16 tile (512 B rows)
#pragma unroll
    for (int j = 0; j < 8; ++j) {
        const int flat = tid + 256 * j;       // 0..2047
        const int r = flat >> 6;              // 32 rows
        const int sg = flat & 63;             // 64 segs of 4 floats
        const float4 xv = *reinterpret_cast<const float4*>(x + (size_t)(row0 + r) * DIM + sg * 4);
        const float4 ev = *reinterpret_cast<const float4*>(emb + (size_t)idxs[r] * DIM + sg * 4);
        const unsigned u0 = __float_as_uint(xv.x - ev.x), u1 = __float_as_uint(xv.y - ev.y);
        const unsigned u2 = __float_as_uint(xv.z - ev.z), u3 = __float_as_uint(xv.w - ev.w);
        const uint2 pk = make_uint2((u0 >> 16) | (u1 & 0xFFFF0000u),
                                    (u2 >> 16) | (u3 & 0xFFFF0000u));
        *reinterpret_cast<uint2*>(sb + r * 512 + ((sg * 8) ^ ((r & 7) << 4))) = pk;
    }

    const ushort_t* Wp[2] = {W1T, W2T};
    f32x4 acc[2][4];

    for (int layer = 0; layer < 2; ++layer) {
        const ushort_t* WT = Wp[layer];
#pragma unroll
        for (int m = 0; m < 2; ++m)
#pragma unroll
            for (int n = 0; n < 4; ++n) {
                f32x4 zz = {0.f, 0.f, 0.f, 0.f};
                acc[m][n] = zz;
            }
        for (int kc = 0; kc < 4; ++kc) {
            __syncthreads();
            // stage WT[:, kc*64..] as [256 out][64 k] bf16 tile @ sb+16K
#pragma unroll
            for (int i = 0; i < 8; ++i) {
                const int g = w * 8 + i;
                async_copy16(WT + (size_t)(g * 8 + rr) * 256 + kc * 64 + egr * 8,
                             sb + 16384 + g * 1024);
            }
            __syncthreads();
#pragma unroll
            for (int ks = 0; ks < 2; ++ks) {
                short8 af[2], bf[4];
#pragma unroll
                for (int m = 0; m < 2; ++m) {
                    const int r = m * 16 + l15;
                    af[m] = *reinterpret_cast<const short8*>(
                        sb + r * 512 + ((((kc * 2 + ks) * 64) + l4 * 16) ^ ((r & 7) << 4)));
                }
#pragma unroll
                for (int n = 0; n < 4; ++n) {
                    const int r = w * 64 + n * 16 + l15;
                    bf[n] = *reinterpret_cast<const short8*>(
                        sb + 16384 + r * 128 + ((ks * 64 + l4 * 16) ^ ((r & 7) << 4)));
                }
#pragma unroll
                for (int m = 0; m < 2; ++m)
#pragma unroll
                    for (int n = 0; n < 4; ++n)
                        acc[m][n] = __builtin_amdgcn_mfma_f32_16x16x32_bf16(af[m], bf[n], acc[m][n], 0, 0, 0);
            }
        }

        if (layer == 0) {
            float b1v[4];
#pragma unroll
            for (int n = 0; n < 4; ++n) b1v[n] = b1[w * 64 + n * 16 + l15];
            __syncthreads();   // all GEMM1 A-tile reads done before overwrite
#pragma unroll
            for (int m = 0; m < 2; ++m)
#pragma unroll
                for (int n = 0; n < 4; ++n)
#pragma unroll
                    for (int j = 0; j < 4; ++j) {
                        const int row = m * 16 + l4 * 4 + j;
                        const int col = w * 64 + n * 16 + l15;
                        const float hv = fmaxf(acc[m][n][j] + b1v[n], 0.f);
                        *reinterpret_cast<ushort_t*>(
                            sb + row * 512 + ((col * 2) ^ ((row & 7) << 4))) =
                            (ushort_t)(__float_as_uint(hv) >> 16);
                    }
            __syncthreads();   // h-tile visible to all waves
        } else {
            float b2v[4];
#pragma unroll
            for (int n = 0; n < 4; ++n) b2v[n] = b2[w * 64 + n * 16 + l15];
#pragma unroll
            for (int m = 0; m < 2; ++m)
#pragma unroll
                for (int n = 0; n < 4; ++n)
#pragma unroll
                    for (int j = 0; j < 4; ++j) {
                        const int row = m * 16 + l4 * 4 + j;
                        const int col = w * 64 + n * 16 + l15;
                        const float ev = emb[(size_t)idxs[row] * DIM + col];
                        z[(size_t)(row0 + row) * DIM + col] = acc[m][n][j] + b2v[n] + ev;
                    }
        }
    }
}

// ---------------- loss: BETA * mean(exact min dist) ----------------
__global__ void loss_kernel(const float* __restrict__ minq, float* __restrict__ loss_out) {
    const int tid = threadIdx.x;
    float s = 0.f;
    for (int i = tid; i < N_TOK; i += 256) s += minq[i];
#pragma unroll
    for (int o = 32; o > 0; o >>= 1) s += __shfl_down(s, o, 64);
    __shared__ float sbf[4];
    if ((tid & 63) == 0) sbf[tid >> 6] = s;
    __syncthreads();
    if (tid == 0) loss_out[0] = BETA_C * ((sbf[0] + sbf[1] + sbf[2] + sbf[3]) / (float)N_TOK);
}

extern "C" void kernel_launch(void* const* d_in, const int* in_sizes, int n_in,
                              void* d_out, int out_size, void* d_ws, size_t ws_size,
                              hipStream_t stream) {
    const float* x   = (const float*)d_in[0];
    const float* emb = (const float*)d_in[1];
    const float* W1  = (const float*)d_in[2];
    const float* b1  = (const float*)d_in[3];
    const float* W2  = (const float*)d_in[4];
    const float* b2  = (const float*)d_in[5];

    float* z_out = (float*)d_out;
    float* loss_out = z_out + (size_t)N_TOK * DIM;

    // workspace (14.1 MB, all disjoint; proven budget >= 17.0 MB):
    //   [0,32K) enorm | [32K,96K) idx | [96K,160K) minq
    //   [160K,288K) W1T | [288K,416K) W2T
    //   [425984, +4M)  E2 [8192][256] bf16
    //   [4620288, +8M) X2 [16384][256] bf16
    //   [13008896, +1M) mg [16384][4] uint4
    char* ws = (char*)d_ws;
    float*    enorm = (float*)(ws);
    int*      idxb  = (int*)(ws + 32768);
    float*    minq  = (float*)(ws + 98304);
    ushort_t* W1T   = (ushort_t*)(ws + 163840);
    ushort_t* W2T   = (ushort_t*)(ws + 294912);
    ushort_t* E2    = (ushort_t*)(ws + 425984);
    ushort_t* X2    = (ushort_t*)(ws + 4620288);
    uint4*    mg    = (uint4*)(ws + 13008896);

    hipLaunchKernelGGL(prep_all_kernel, dim3(6656), dim3(256), 0, stream,
                       x, emb, W1, W2, X2, E2, enorm, W1T, W2T);
    hipLaunchKernelGGL(dist_kernel, dim3(N_TOK / 128, NSPLIT), dim3(256), 0, stream,
                       X2, E2, enorm, mg);
    hipLaunchKernelGGL(merge_fixup_kernel, dim3(N_TOK / 4), dim3(256), 0, stream,
                       x, emb, mg, idxb, minq);
    hipLaunchKernelGGL(fused_mlp_kernel, dim3(N_TOK / 32), dim3(256), 0, stream,
                       x, emb, idxb, W1T, W2T, b1, b2, z_out);
    hipLaunchKernelGGL(loss_kernel, dim3(1), dim3(256), 0, stream, minq, loss_out);
}